// Round 5
// baseline (303.574 us; speedup 1.0000x reference)
//
#include <hip/hip_runtime.h>
#include <hip/hip_bf16.h>
#include <stdint.h>

#define M_DIM 4096
#define N_DIM 10000
#define K_DIM 1024
#define GM (M_DIM / 128)            // 32 row-tiles
#define GN ((N_DIM + 127) / 128)    // 79 col-tiles (last covers 9984..10111, stores predicated)
#define NT (K_DIM / 32)             // 32 K-tiles of BK=32

typedef __attribute__((ext_vector_type(8))) short bf16x8;
typedef __attribute__((ext_vector_type(4))) float f32x4;

#define BAR()      asm volatile("s_barrier" ::: "memory")
#define WAITVM4()  asm volatile("s_waitcnt vmcnt(4)" ::: "memory")
#define WAITVM0()  asm volatile("s_waitcnt vmcnt(0)" ::: "memory")
#define WAITLGKM() asm volatile("s_waitcnt lgkmcnt(0)" ::: "memory")

// async global->LDS, 16B per lane. LDS dest must be wave-uniform base + lane*16.
__device__ __forceinline__ void async_ld16(const void* g, void* l) {
    __builtin_amdgcn_global_load_lds(
        (const __attribute__((address_space(1))) unsigned int*)g,
        (__attribute__((address_space(3))) unsigned int*)l,
        16, 0, 0);
}

__device__ __forceinline__ unsigned short f2bf(float f) {
    unsigned u = __float_as_uint(f);
    unsigned r = (u + 0x7FFFu + ((u >> 16) & 1u)) >> 16;  // RNE
    return (unsigned short)r;
}

// Wave-per-row: fp32 -> bf16 convert + exact fp32 ||x||^2. Grid-stride over
// the 14096 rows (feat then centers). 1024 floats/row = 64 lanes x 4 float4.
__global__ __launch_bounds__(256) void prep_rows(
    const float* __restrict__ feat, const float* __restrict__ cent,
    unsigned short* __restrict__ featbf, unsigned short* __restrict__ centbf,
    float* __restrict__ fsq, float* __restrict__ csq)
{
    const int wlane = threadIdx.x & 63;
    const int wid   = blockIdx.x * 4 + (threadIdx.x >> 6);
    const int nw    = gridDim.x * 4;
    for (int row = wid; row < M_DIM + N_DIM; row += nw) {
        const float* in;
        unsigned short* outb;
        float* sqp;
        if (row < M_DIM) {
            in = feat + (size_t)row * K_DIM;
            outb = featbf + (size_t)row * K_DIM;
            sqp = fsq + row;
        } else {
            const int r2 = row - M_DIM;
            in = cent + (size_t)r2 * K_DIM;
            outb = centbf + (size_t)r2 * K_DIM;
            sqp = csq + r2;
        }
        float s = 0.f;
        #pragma unroll
        for (int c = 0; c < 4; c++) {
            float4 v = ((const float4*)in)[wlane + c * 64];
            ushort4 pk;
            pk.x = f2bf(v.x); pk.y = f2bf(v.y); pk.z = f2bf(v.z); pk.w = f2bf(v.w);
            ((ushort4*)outb)[wlane + c * 64] = pk;
            s += v.x * v.x + v.y * v.y + v.z * v.z + v.w * v.w;
        }
        #pragma unroll
        for (int off = 32; off > 0; off >>= 1) s += __shfl_down(s, off, 64);
        if (wlane == 0) *sqp = s;
    }
}

// C[m][n] = sum_k A[m][k]*B[n][k] (both K-major), epilogue adds norms.
//
// Rev 5: TLP-first. 128x128 tile, 4 waves (2x2, wave owns 64x64 = 4x4 frags of
// mfma 16x16x32 bf16). Small footprint: 32 KB LDS (2x16KB dbuf) +
// __launch_bounds__(256,4) reg cap -> 4 independent blocks/CU (16 waves/CU).
// Rationale: 4 schedule variants at 1-2.4 blocks/CU all pinned at 28-30%
// MfmaUtil; stalls (vmcnt drain, barriers, epilogue store-drain, prologue)
// must be absorbed by OTHER resident blocks (m114 wave-level overlap), not
// intra-block choreography. Grid 2528 blocks also kills the 2.5-round
// quantization (was: 3rd round ran 128 blocks on 256 CUs).
//
// K-loop = proven m97 structure: {stage t+1 -> buf^1 | vmcnt(4) | BAR |
// 16 MFMA from buf | BAR}. Cross-wave publish: each wave passes its own
// vmcnt(4) (own 4 loads of t+1 issued last iter retired) before the pre-
// compute BAR, so after the BAR every wave's staged data is visible.
//
// T2 swizzle: ds_read_b128 at 64B row stride is 8-way bank-conflicted
// (measured 1.1e7 conflict cycles at this geometry in round 0); reads XOR the
// 16B-slot index with row bits [2:1]. global_load_lds writes LDS linearly, so
// the same XOR is pre-applied to the per-lane GLOBAL k-offset at staging
// (involution: linear dest + inv-swz source + swz read).
__global__ __launch_bounds__(256, 4) void gemm_bt(
    const unsigned short* __restrict__ A,   // featbf [M][K]
    const unsigned short* __restrict__ B,   // centbf [N][K]
    const float* __restrict__ fsq, const float* __restrict__ csq,
    float* __restrict__ out)
{
    // 2 buffers x (A 128x32 @ 0..8KB, B 128x32 @ 8..16KB) = 32 KB
    __shared__ unsigned short smem[16384];

    const int tid  = threadIdx.x;
    const int lane = tid & 63;
    const int wave = tid >> 6;            // 0..3
    const int wm = wave & 1;              // 2 M-warps x 64 rows
    const int wn = wave >> 1;             // 2 N-warps x 64 cols
    const int mlane = lane & 15;
    const int quad  = lane >> 4;
    const int qx  = (quad ^ ((mlane >> 1) & 3)) << 4;   // swizzled 16B slot

    // T1: bijective XCD swizzle (2528 = 8 x 316). Each XCD gets ~10
    // consecutive bn panels (~2.5 MB of B) across all bm -> B L2-resident.
    const int bid = blockIdx.x;
    const int xcd = bid & 7;
    const int idx = bid >> 3;                     // 0..315
    const int r0  = xcd * 316 + idx;
    const int bm  = r0 & 31;
    const int bn  = r0 >> 5;                      // 0..78

    const int arow_base = bm * 128;
    const int brow_base = bn * 128;

    // staging: 4 loads/thread/tile (A x2, B x2). A region 8KB = 512 slots of
    // 16B, B likewise. slot s = i*256+tid; row = s>>2 (0..127), sc = s&3;
    // global k-offset pre-swizzled: k = (sc ^ ((row>>1)&3)) * 8 shorts.
    const unsigned short* gA[2];
    const unsigned short* gB[2];
    int ldsA[2], ldsB[2];
    #pragma unroll
    for (int i = 0; i < 2; i++) {
        const int s   = i * 256 + tid;            // 0..511
        const int row = s >> 2;                   // 0..127
        const int sc  = s & 3;
        const int kof = (sc ^ ((row >> 1) & 3)) << 3;
        gA[i] = A + (size_t)(arow_base + row) * K_DIM + kof;
        int br = brow_base + row; if (br > N_DIM - 1) br = N_DIM - 1;
        gB[i] = B + (size_t)br * K_DIM + kof;
        ldsA[i] = s * 16;
        ldsB[i] = 8192 + s * 16;
    }

    #define STAGE(t2, nbb)                                                    \
        do {                                                                  \
            async_ld16(gA[0] + (size_t)(t2) * 32, (char*)smem + (nbb) + ldsA[0]); \
            async_ld16(gA[1] + (size_t)(t2) * 32, (char*)smem + (nbb) + ldsA[1]); \
            async_ld16(gB[0] + (size_t)(t2) * 32, (char*)smem + (nbb) + ldsB[0]); \
            async_ld16(gB[1] + (size_t)(t2) * 32, (char*)smem + (nbb) + ldsB[1]); \
        } while (0)

    f32x4 acc[4][4];
    #pragma unroll
    for (int i = 0; i < 4; i++)
        #pragma unroll
        for (int j = 0; j < 4; j++) {
            f32x4 z = {0.f, 0.f, 0.f, 0.f};
            acc[i][j] = z;
        }

    // ds_read bases (bytes within a buffer); frag i at +i*1024 (16 rows x 64B)
    const int aBase = (wm * 64 + mlane) * 64 + qx;
    const int bBase = 8192 + (wn * 64 + mlane) * 64 + qx;

    // prologue: stage tile 0 into buf0
    STAGE(0, 0);

    for (int t = 0; t < NT; ++t) {
        const char* base = (const char*)smem + (t & 1) * 16384;
        const int  nb    = ((t + 1) & 1) * 16384;
        if (t + 1 < NT) { STAGE(t + 1, nb); WAITVM4(); }
        else            { WAITVM0(); }
        BAR();   // publish: every wave passed its own vmcnt -> tile t visible

        bf16x8 af[4], bfv[4];
        #pragma unroll
        for (int i = 0; i < 4; i++) {
            af[i]  = *(const bf16x8*)(base + aBase + i * 1024);
            bfv[i] = *(const bf16x8*)(base + bBase + i * 1024);
        }
        __builtin_amdgcn_s_setprio(1);
        #pragma unroll
        for (int i = 0; i < 4; i++)
            #pragma unroll
            for (int j = 0; j < 4; j++)
                acc[i][j] = __builtin_amdgcn_mfma_f32_16x16x32_bf16(
                    af[i], bfv[j], acc[i][j], 0, 0, 0);
        __builtin_amdgcn_s_setprio(0);
        BAR();   // readers of buf done before t+2's stage overwrites it
    }
    #undef STAGE

    // epilogue: fold norms, transpose 16x64 chunks through LDS, NT f32x4
    // stores (256B contiguous per row segment). Per-wave scratch 16 x stride-68
    // = 4 waves x 1088 f32 = 17.4 KB, fits in the 32 KB smem (loop done).
    float* W = (float*)smem + wave * 1088;
    const int rbase0 = arow_base + wm * 64;
    const int cbase  = brow_base + wn * 64 + mlane;
    const int rb_col4 = mlane * 4;
    const int gcol4  = brow_base + wn * 64 + rb_col4;
    const bool colok = gcol4 < N_DIM;             // 4-aligned, N%4==0 -> +3 safe

    #pragma unroll
    for (int i = 0; i < 4; i++) {
        float frow[4];
        #pragma unroll
        for (int r = 0; r < 4; r++)
            frow[r] = -0.5f * fsq[rbase0 + i * 16 + quad * 4 + r];
        #pragma unroll
        for (int j = 0; j < 4; j++) {
            int col = cbase + j * 16;
            float cs = -0.5f * csq[col < N_DIM ? col : (N_DIM - 1)];
            #pragma unroll
            for (int r = 0; r < 4; r++)
                W[(quad * 4 + r) * 68 + j * 16 + mlane] = acc[i][j][r] + frow[r] + cs;
        }
        WAITLGKM();  // writes visible to own-wave reads
        #pragma unroll
        for (int s = 0; s < 4; s++) {
            int rl = s * 4 + quad;
            f32x4 v = *(const f32x4*)&W[rl * 68 + rb_col4];
            if (colok) {
                int grow = rbase0 + i * 16 + rl;
                __builtin_nontemporal_store(v, (f32x4*)&out[(size_t)grow * N_DIM + gcol4]);
            }
        }
        WAITLGKM();  // reads done before next i overwrites W
    }
}

extern "C" void kernel_launch(void* const* d_in, const int* in_sizes, int n_in,
                              void* d_out, int out_size, void* d_ws, size_t ws_size,
                              hipStream_t stream) {
    const float* feat = (const float*)d_in[0];   // [4096,1024]
    const float* cent = (const float*)d_in[1];   // [10000,1024]
    float* out = (float*)d_out;                  // [4096,10000]

    char* ws = (char*)d_ws;
    unsigned short* featbf = (unsigned short*)ws;                         // 8,388,608 B
    unsigned short* centbf = (unsigned short*)(ws + 8388608);             // 20,480,000 B
    float* fsq = (float*)(ws + 8388608 + 20480000);                       // 16,384 B
    float* csq = (float*)(ws + 8388608 + 20480000 + 16384);               // 40,000 B

    prep_rows<<<1024, 256, 0, stream>>>(feat, cent, featbf, centbf, fsq, csq);

    gemm_bt<<<GM * GN, 256, 0, stream>>>(featbf, centbf, fsq, csq, out);
}

// Round 6
// 290.286 us; speedup vs baseline: 1.0458x; 1.0458x over previous
//
#include <hip/hip_runtime.h>
#include <hip/hip_bf16.h>
#include <stdint.h>

#define M_DIM 4096
#define N_DIM 10000
#define K_DIM 1024
#define GM (M_DIM / 128)            // 32 row-tiles
#define GN ((N_DIM + 127) / 128)    // 79 col-tiles (last covers 9984..10111, stores predicated)
#define NT (K_DIM / 32)             // 32 K-tiles of BK=32

typedef __attribute__((ext_vector_type(8))) short bf16x8;
typedef __attribute__((ext_vector_type(4))) float f32x4;

#define BAR()      asm volatile("s_barrier" ::: "memory")
#define WAITVM4()  asm volatile("s_waitcnt vmcnt(4)" ::: "memory")
#define WAITVM0()  asm volatile("s_waitcnt vmcnt(0)" ::: "memory")
#define WAITLGKM() asm volatile("s_waitcnt lgkmcnt(0)" ::: "memory")

// async global->LDS, 16B per lane. LDS dest must be wave-uniform base + lane*16.
__device__ __forceinline__ void async_ld16(const void* g, void* l) {
    __builtin_amdgcn_global_load_lds(
        (const __attribute__((address_space(1))) unsigned int*)g,
        (__attribute__((address_space(3))) unsigned int*)l,
        16, 0, 0);
}

__device__ __forceinline__ unsigned short f2bf(float f) {
    unsigned u = __float_as_uint(f);
    unsigned r = (u + 0x7FFFu + ((u >> 16) & 1u)) >> 16;  // RNE
    return (unsigned short)r;
}

// Wave-per-row: fp32 -> bf16 convert + exact fp32 ||x||^2. Grid-stride over
// the 14096 rows (feat then centers). 1024 floats/row = 64 lanes x 4 float4.
__global__ __launch_bounds__(256) void prep_rows(
    const float* __restrict__ feat, const float* __restrict__ cent,
    unsigned short* __restrict__ featbf, unsigned short* __restrict__ centbf,
    float* __restrict__ fsq, float* __restrict__ csq)
{
    const int wlane = threadIdx.x & 63;
    const int wid   = blockIdx.x * 4 + (threadIdx.x >> 6);
    const int nw    = gridDim.x * 4;
    for (int row = wid; row < M_DIM + N_DIM; row += nw) {
        const float* in;
        unsigned short* outb;
        float* sqp;
        if (row < M_DIM) {
            in = feat + (size_t)row * K_DIM;
            outb = featbf + (size_t)row * K_DIM;
            sqp = fsq + row;
        } else {
            const int r2 = row - M_DIM;
            in = cent + (size_t)r2 * K_DIM;
            outb = centbf + (size_t)r2 * K_DIM;
            sqp = csq + r2;
        }
        float s = 0.f;
        #pragma unroll
        for (int c = 0; c < 4; c++) {
            float4 v = ((const float4*)in)[wlane + c * 64];
            ushort4 pk;
            pk.x = f2bf(v.x); pk.y = f2bf(v.y); pk.z = f2bf(v.z); pk.w = f2bf(v.w);
            ((ushort4*)outb)[wlane + c * 64] = pk;
            s += v.x * v.x + v.y * v.y + v.z * v.z + v.w * v.w;
        }
        #pragma unroll
        for (int off = 32; off > 0; off >>= 1) s += __shfl_down(s, off, 64);
        if (wlane == 0) *sqp = s;
    }
}

// C[m][n] = sum_k A[m][k]*B[n][k] (both K-major), epilogue adds norms.
//
// Rev 6: TLP + deep prefetch combined. 128x128 tile, 4 waves (2x2, wave owns
// 64x64 = 4x4 frags of mfma 16x16x32 bf16). TRIPLE-buffered LDS (3 x 16 KB =
// 48 KB) with staging TWO K-tiles ahead -> loads get >=2 tile-periods to land
// (>> ~900cy HBM latency), so the per-tile period is no longer pinned to the
// load round-trip (rev 0/5's limiter: 1-deep prefetch, vmcnt wait = period).
// 48 KB -> 3 blocks/CU (12 waves/CU): 3 independent waves per SIMD fill each
// other's barrier/LDS gaps (rev 2-4's limiter: 2 barrier-locked waves/SIMD).
//
// K-loop: { stage(t+2 -> buf[(t+2)%3]) | vmcnt(4) [t+1 landed, t+2 in flight]
//           | BAR | 8 ds_read + 16 MFMA from buf[t%3] | BAR }.
// Buffer identity: (t+2)%3 == (t-1)%3, i.e. stage targets the buffer read at
// t-1, whose readers all finished before t-1's end-BAR -> race-free.
// Tail: t=NT-2 waits vmcnt(0) (last tile's 4 loads), t=NT-1 no wait.
//
// T1 (padded bijective XCD map): grid 2560 = 8 x 320; xcd = bid&7 owns a
// contiguous bn range (10 panels for xcd<7, 9 for xcd 7; 32 blocks idle).
// Within an XCD, k = bid>>3 sweeps bn FAST, bm SLOW: the XCD's B panels
// (<=2.6 MB) stay L2-resident for the whole kernel and each A panel (256 KB)
// is L2-reused across the bn sweep (rev 5's bm-inner order streamed all of A
// per panel -> FETCH 306 MB; this restores ~110 MB).
//
// T2 swizzle: ds_read_b128 at 64B row stride is 8-way bank-conflicted; reads
// XOR the 16B-slot index with row bits [2:1]. global_load_lds writes LDS
// linearly, so the same XOR is pre-applied to the per-lane GLOBAL k-offset at
// staging (involution: linear dest + inv-swz source + swz read).
__global__ __launch_bounds__(256, 4) void gemm_bt(
    const unsigned short* __restrict__ A,   // featbf [M][K]
    const unsigned short* __restrict__ B,   // centbf [N][K]
    const float* __restrict__ fsq, const float* __restrict__ csq,
    float* __restrict__ out)
{
    // 3 buffers x (A 128x32 @ 0..8KB, B 128x32 @ 8..16KB) = 48 KB
    __shared__ unsigned short smem[24576];

    const int tid  = threadIdx.x;
    const int lane = tid & 63;
    const int wave = tid >> 6;            // 0..3
    const int wm = wave & 1;              // 2 M-warps x 64 rows
    const int wn = wave >> 1;             // 2 N-warps x 64 cols
    const int mlane = lane & 15;
    const int quad  = lane >> 4;
    const int qx  = (quad ^ ((mlane >> 1) & 3)) << 4;   // swizzled 16B slot

    // T1: padded bijective XCD map. 2560 blocks; xcd<7 -> 10 bn panels from
    // xcd*10; xcd==7 -> 9 panels from 70. k sweeps bn fast / bm slow.
    const int bid = blockIdx.x;
    const int xcd = bid & 7;
    const int k   = bid >> 3;                     // 0..319
    const int W   = (xcd < 7) ? 10 : 9;
    if (k >= 32 * W) return;                      // block-uniform idle exit
    const int bm  = k / W;                        // 0..31
    const int bn  = ((xcd < 7) ? xcd * 10 : 70) + (k - bm * W);

    const int arow_base = bm * 128;
    const int brow_base = bn * 128;

    // staging: 4 loads/thread/tile (A x2, B x2). slot s = i*256+tid;
    // row = s>>2 (0..127), sc = s&3; global k-offset pre-swizzled:
    // k = (sc ^ ((row>>1)&3)) * 8 shorts.
    const unsigned short* gA[2];
    const unsigned short* gB[2];
    int ldsA[2], ldsB[2];
    #pragma unroll
    for (int i = 0; i < 2; i++) {
        const int s   = i * 256 + tid;            // 0..511
        const int row = s >> 2;                   // 0..127
        const int sc  = s & 3;
        const int kof = (sc ^ ((row >> 1) & 3)) << 3;
        gA[i] = A + (size_t)(arow_base + row) * K_DIM + kof;
        int br = brow_base + row; if (br > N_DIM - 1) br = N_DIM - 1;
        gB[i] = B + (size_t)br * K_DIM + kof;
        ldsA[i] = s * 16;
        ldsB[i] = 8192 + s * 16;
    }

    #define STAGE(t2, nbb)                                                    \
        do {                                                                  \
            async_ld16(gA[0] + (size_t)(t2) * 32, (char*)smem + (nbb) + ldsA[0]); \
            async_ld16(gA[1] + (size_t)(t2) * 32, (char*)smem + (nbb) + ldsA[1]); \
            async_ld16(gB[0] + (size_t)(t2) * 32, (char*)smem + (nbb) + ldsB[0]); \
            async_ld16(gB[1] + (size_t)(t2) * 32, (char*)smem + (nbb) + ldsB[1]); \
        } while (0)

    f32x4 acc[4][4];
    #pragma unroll
    for (int i = 0; i < 4; i++)
        #pragma unroll
        for (int j = 0; j < 4; j++) {
            f32x4 z = {0.f, 0.f, 0.f, 0.f};
            acc[i][j] = z;
        }

    // ds_read bases (bytes within a buffer); frag i at +i*1024 (16 rows x 64B)
    const int aBase = (wm * 64 + mlane) * 64 + qx;
    const int bBase = 8192 + (wn * 64 + mlane) * 64 + qx;

    // prologue: stage tiles 0,1 into bufs 0,1; vmcnt(4) -> tile 0 landed,
    // tile 1 in flight
    STAGE(0, 0);
    STAGE(1, 16384);
    WAITVM4();
    BAR();

    int cur = 0;            // byte base of buf[t%3]
    int prv = 32768;        // byte base of buf[(t-1)%3] == stage target (t+2)%3
    for (int t = 0; t < NT; ++t) {
        if (t + 2 < NT) { STAGE(t + 2, prv); WAITVM4(); }
        else if (t == NT - 2) { WAITVM0(); }
        BAR();   // publish: every wave passed its vmcnt -> tile t (and t+1 later) visible

        const char* base = (const char*)smem + cur;
        bf16x8 af[4], bfv[4];
        #pragma unroll
        for (int i = 0; i < 4; i++) {
            af[i]  = *(const bf16x8*)(base + aBase + i * 1024);
            bfv[i] = *(const bf16x8*)(base + bBase + i * 1024);
        }
        __builtin_amdgcn_s_setprio(1);
        #pragma unroll
        for (int i = 0; i < 4; i++)
            #pragma unroll
            for (int j = 0; j < 4; j++)
                acc[i][j] = __builtin_amdgcn_mfma_f32_16x16x32_bf16(
                    af[i], bfv[j], acc[i][j], 0, 0, 0);
        __builtin_amdgcn_s_setprio(0);
        BAR();   // readers of buf[t%3] done before iter t+1 stages into it

        int nxt = cur + 16384; if (nxt > 32768) nxt = 0;
        prv = cur; cur = nxt;
    }
    #undef STAGE

    // epilogue: fold norms, transpose 16x64 chunks through LDS, NT f32x4
    // stores (256B contiguous per row segment). Per-wave scratch 16 x stride-68
    // = 4 waves x 1088 f32 = 17.4 KB, fits in the 48 KB smem (loop done).
    float* W2 = (float*)smem + wave * 1088;
    const int rbase0 = arow_base + wm * 64;
    const int cbase  = brow_base + wn * 64 + mlane;
    const int rb_col4 = mlane * 4;
    const int gcol4  = brow_base + wn * 64 + rb_col4;
    const bool colok = gcol4 < N_DIM;             // 4-aligned, N%4==0 -> +3 safe

    #pragma unroll
    for (int i = 0; i < 4; i++) {
        float frow[4];
        #pragma unroll
        for (int r = 0; r < 4; r++)
            frow[r] = -0.5f * fsq[rbase0 + i * 16 + quad * 4 + r];
        #pragma unroll
        for (int j = 0; j < 4; j++) {
            int col = cbase + j * 16;
            float cs = -0.5f * csq[col < N_DIM ? col : (N_DIM - 1)];
            #pragma unroll
            for (int r = 0; r < 4; r++)
                W2[(quad * 4 + r) * 68 + j * 16 + mlane] = acc[i][j][r] + frow[r] + cs;
        }
        WAITLGKM();  // writes visible to own-wave reads
        #pragma unroll
        for (int s = 0; s < 4; s++) {
            int rl = s * 4 + quad;
            f32x4 v = *(const f32x4*)&W2[rl * 68 + rb_col4];
            if (colok) {
                int grow = rbase0 + i * 16 + rl;
                __builtin_nontemporal_store(v, (f32x4*)&out[(size_t)grow * N_DIM + gcol4]);
            }
        }
        WAITLGKM();  // reads done before next i overwrites W2
    }
}

extern "C" void kernel_launch(void* const* d_in, const int* in_sizes, int n_in,
                              void* d_out, int out_size, void* d_ws, size_t ws_size,
                              hipStream_t stream) {
    const float* feat = (const float*)d_in[0];   // [4096,1024]
    const float* cent = (const float*)d_in[1];   // [10000,1024]
    float* out = (float*)d_out;                  // [4096,10000]

    char* ws = (char*)d_ws;
    unsigned short* featbf = (unsigned short*)ws;                         // 8,388,608 B
    unsigned short* centbf = (unsigned short*)(ws + 8388608);             // 20,480,000 B
    float* fsq = (float*)(ws + 8388608 + 20480000);                       // 16,384 B
    float* csq = (float*)(ws + 8388608 + 20480000 + 16384);               // 40,000 B

    prep_rows<<<1024, 256, 0, stream>>>(feat, cent, featbf, centbf, fsq, csq);

    gemm_bt<<<2560, 256, 0, stream>>>(featbf, centbf, fsq, csq, out);
}